// Round 13
// baseline (251.879 us; speedup 1.0000x reference)
//
#include <hip/hip_runtime.h>
#include <hip/hip_bf16.h>
#include <cstdint>
#include <cstddef>

#define NUM_CLASS 1000
#define NPAD      1024
#define LOW_DIM   128
#define B_UPD     1024
#define B_SIM     65536

typedef short bf16x8 __attribute__((ext_vector_type(8)));
typedef float f32x4  __attribute__((ext_vector_type(4)));

__device__ __forceinline__ unsigned short f2bf(float f) {
  union { float f; unsigned u; } a; a.f = f;
  unsigned u = a.u;
  return (unsigned short)((u + 0x7fffu + ((u >> 16) & 1u)) >> 16);  // RNE
}

// ---------- kernel 1: per-class EMA (ballot scan) + L2 norm -> fragment-swizzled bf16 ----------
// Updates to different labels commute, so per-class in-order processing
// reproduces the reference lax.scan exactly.
// Output layout = MFMA B-operand fragment order (lane l: col=l&15, k=(l>>4)*8+e):
//   slot[((g*4 + kk)*64 + l) * 8 + e]  (ushort units)
//   holds logical B[row = g*16 + (l&15)][k = kk*32 + (l>>4)*8 + e]
__global__ void proto_update_kernel(const float* __restrict__ pred_feat,
                                    const int*   __restrict__ labels,
                                    const float* __restrict__ protos_in,
                                    unsigned short* __restrict__ protos_sw) {
  int c = blockIdx.x;    // 0..1023
  int d = threadIdx.x;   // 0..127
  float p = 0.0f;
  if (c < NUM_CLASS) {
    p = protos_in[c * LOW_DIM + d];
    #pragma unroll 4
    for (int k = 0; k < B_UPD / 64; ++k) {
      int lab = labels[k * 64 + (d & 63)];
      unsigned long long m = __ballot(lab == c);   // wave-uniform
      while (m) {
        int b = __builtin_ctzll(m);
        m &= (m - 1);
        p = 0.99f * p + 0.01f * pred_feat[(size_t)(k * 64 + b) * LOW_DIM + d];
      }
    }
  }
  float sq = p * p;
  #pragma unroll
  for (int o = 1; o < 64; o <<= 1) sq += __shfl_xor(sq, o, 64);
  __shared__ float wsum[2];
  if ((d & 63) == 0) wsum[d >> 6] = sq;
  __syncthreads();
  float total = wsum[0] + wsum[1];
  unsigned short v = f2bf(p / fmaxf(sqrtf(total), 1e-12f));  // c>=1000 -> 0
  int g = c >> 4, r = c & 15, kk = d >> 5, j = (d >> 3) & 3, e = d & 7;
  protos_sw[(size_t)((g * 4 + kk) * 64 + j * 16 + r) * 8 + e] = v;
}

// ---------- kernel 2: C[65536,1000] = A(f32->bf16) @ B^T, BM=32 x full-N ----------
// R6 structure (best: 73.9 us) with ONE change: the per-wave epilogue
// transpose runs in two 8-row passes, shrinking the buffer to 4224 B/wave
// -> block LDS 33.8 KB (A-tile unioned, protected by the post-K barrier
// exactly as in R6) -> with __launch_bounds__(512,8) capping VGPR at 64
// (R12 measured this body at 64 VGPR) we get 4 blocks/CU = 32 waves/CU
// (R6: 2 blocks, 16 waves). Store addresses/order/width unchanged
// (512B chunks per row per wave). Occupancy was the only lever that ever
// produced a large win (R3->R4, 1->2 blocks, +22%).
#define BM   32
#define TPB2 512
#define CPAD 132                 // epilogue f32 LDS row stride (128+4)
#define EPW8 (8 * CPAD)          // floats per wave epilogue region (4224 B)

__global__ __launch_bounds__(TPB2, 8)
void gemm_sim_kernel(const float* __restrict__ A,
                     const unsigned short* __restrict__ Bsw,
                     float* __restrict__ C) {
  __shared__ float Tbuf[8 * EPW8];   // 33792 B (union: first 8 KB = A-tile)
  unsigned char* Als = reinterpret_cast<unsigned char*>(Tbuf);
  int t  = threadIdx.x;
  int m0 = blockIdx.x * BM;

  // ---- stage A: exactly 32 rows x 128 f32 -> bf16, XOR-swizzled (rows 256 B) ----
  {
    int row = t >> 4, c8 = t & 15;   // 512 threads = 32 rows x 16 slots
    const float4* s = reinterpret_cast<const float4*>(A + (size_t)(m0 + row) * LOW_DIM + c8 * 8);
    float4 v0 = s[0], v1 = s[1];
    uint4 q;
    q.x = f2bf(v0.x) | ((unsigned)f2bf(v0.y) << 16);
    q.y = f2bf(v0.z) | ((unsigned)f2bf(v0.w) << 16);
    q.z = f2bf(v1.x) | ((unsigned)f2bf(v1.y) << 16);
    q.w = f2bf(v1.z) | ((unsigned)f2bf(v1.w) << 16);
    *reinterpret_cast<uint4*>(Als + row * 256 + ((c8 * 16) ^ ((row & 7) << 4))) = q;
  }
  __syncthreads();

  int lane = t & 63;
  int w    = t >> 6;
  int lr   = lane & 15;
  int hi   = lane >> 4;            // 0..3
  int lkb  = hi * 16;

  f32x4 acc[2][8];
  #pragma unroll
  for (int m = 0; m < 2; ++m)
    #pragma unroll
    for (int n = 0; n < 8; ++n)
      acc[m][n] = (f32x4){0.f, 0.f, 0.f, 0.f};

  #pragma unroll
  for (int kk = 0; kk < 4; ++kk) {             // K = 4 x 32
    int kb = kk * 64 + lkb;
    bf16x8 af[2];
    #pragma unroll
    for (int m = 0; m < 2; ++m) {
      int row = m * 16 + lr;
      af[m] = *reinterpret_cast<const bf16x8*>(Als + row * 256 + (kb ^ ((row & 7) << 4)));
    }
    #pragma unroll
    for (int n = 0; n < 8; ++n) {
      int g = w * 8 + n;                       // 16-class group
      bf16x8 bf = *reinterpret_cast<const bf16x8*>(
          Bsw + ((size_t)(g * 4 + kk) * 64 + lane) * 8);   // coalesced 1KB/wave
      #pragma unroll
      for (int m = 0; m < 2; ++m)
        acc[m][n] = __builtin_amdgcn_mfma_f32_16x16x32_bf16(af[m], bf, acc[m][n], 0, 0, 0);
    }
  }
  __syncthreads();   // A-tile dead for ALL waves before epilogue reuses the union

  // ---- per-wave-private epilogue: two 8-row transpose passes (wave-local,
  //      in-order DS). D layout: row = hi*4 + r, col = lane&15. Pass p
  //      handles rows 8p..8p+7 (lanes with hi>>1 == p write; buffer row =
  //      (hi&1)*4 + r; 32 active lanes hit 32 distinct banks). Readback +
  //      512B-chunk f32x4 stores identical addresses/order to R6. ----
  float* myT = Tbuf + w * EPW8;
  #pragma unroll
  for (int m = 0; m < 2; ++m) {
    #pragma unroll
    for (int p = 0; p < 2; ++p) {
      if ((hi >> 1) == p) {
        int rbase = (hi & 1) * 4;
        #pragma unroll
        for (int n = 0; n < 8; ++n) {
          #pragma unroll
          for (int r = 0; r < 4; ++r)
            myT[(rbase + r) * CPAD + n * 16 + lr] = acc[m][n][r];
        }
      }
      #pragma unroll
      for (int it = 0; it < 4; ++it) {
        int idx = it * 64 + lane;
        int row = idx >> 5, c4 = idx & 31;     // row 0..7, f32x4 chunk 0..31
        f32x4 v = *reinterpret_cast<const f32x4*>(myT + row * CPAD + c4 * 4);
        int col = w * 128 + c4 * 4;
        if (col < NUM_CLASS) {   // only wave 7 tail masked; 1000 % 4 == 0
          *reinterpret_cast<f32x4*>(
              C + (size_t)(m0 + m * 16 + p * 8 + row) * NUM_CLASS + col) = v;
        }
      }
    }
  }
}

extern "C" void kernel_launch(void* const* d_in, const int* in_sizes, int n_in,
                              void* d_out, int out_size, void* d_ws, size_t ws_size,
                              hipStream_t stream) {
  const float* pred_feat = (const float*)d_in[0];   // [1024,128]
  const int*   labels    = (const int*)d_in[1];     // [1024]
  const float* protos    = (const float*)d_in[2];   // [1000,128]
  const float* feat      = (const float*)d_in[3];   // [65536,128]
  float* out = (float*)d_out;                       // [65536,1000]

  unsigned short* protos_sw = (unsigned short*)d_ws;  // 256 KB fragment-swizzled

  proto_update_kernel<<<NPAD, 128, 0, stream>>>(pred_feat, labels, protos, protos_sw);
  gemm_sim_kernel<<<B_SIM / BM, TPB2, 0, stream>>>(feat, protos_sw, out);
}

// Round 14
// 123.956 us; speedup vs baseline: 2.0320x; 2.0320x over previous
//
#include <hip/hip_runtime.h>
#include <hip/hip_bf16.h>
#include <cstdint>
#include <cstddef>

#define NUM_CLASS 1000
#define NPAD      1024
#define LOW_DIM   128
#define B_UPD     1024
#define B_SIM     65536

typedef short bf16x8 __attribute__((ext_vector_type(8)));
typedef float f32x4  __attribute__((ext_vector_type(4)));

__device__ __forceinline__ unsigned short f2bf(float f) {
  union { float f; unsigned u; } a; a.f = f;
  unsigned u = a.u;
  return (unsigned short)((u + 0x7fffu + ((u >> 16) & 1u)) >> 16);  // RNE
}

// ---------- kernel 1: per-class EMA (ballot scan) + L2 norm -> fragment-swizzled bf16 ----------
// Updates to different labels commute, so per-class in-order processing
// reproduces the reference lax.scan exactly.
// Output layout = MFMA B-operand fragment order (lane l: col=l&15, k=(l>>4)*8+e):
//   slot[((g*4 + kk)*64 + l) * 8 + e]  (ushort units)
//   holds logical B[row = g*16 + (l&15)][k = kk*32 + (l>>4)*8 + e]
__global__ void proto_update_kernel(const float* __restrict__ pred_feat,
                                    const int*   __restrict__ labels,
                                    const float* __restrict__ protos_in,
                                    unsigned short* __restrict__ protos_sw) {
  int c = blockIdx.x;    // 0..1023
  int d = threadIdx.x;   // 0..127
  float p = 0.0f;
  if (c < NUM_CLASS) {
    p = protos_in[c * LOW_DIM + d];
    #pragma unroll 4
    for (int k = 0; k < B_UPD / 64; ++k) {
      int lab = labels[k * 64 + (d & 63)];
      unsigned long long m = __ballot(lab == c);   // wave-uniform
      while (m) {
        int b = __builtin_ctzll(m);
        m &= (m - 1);
        p = 0.99f * p + 0.01f * pred_feat[(size_t)(k * 64 + b) * LOW_DIM + d];
      }
    }
  }
  float sq = p * p;
  #pragma unroll
  for (int o = 1; o < 64; o <<= 1) sq += __shfl_xor(sq, o, 64);
  __shared__ float wsum[2];
  if ((d & 63) == 0) wsum[d >> 6] = sq;
  __syncthreads();
  float total = wsum[0] + wsum[1];
  unsigned short v = f2bf(p / fmaxf(sqrtf(total), 1e-12f));  // c>=1000 -> 0
  int g = c >> 4, r = c & 15, kk = d >> 5, j = (d >> 3) & 3, e = d & 7;
  protos_sw[(size_t)((g * 4 + kk) * 64 + j * 16 + r) * 8 + e] = v;
}

// ---------- kernel 2: C[65536,1000] = A(f32->bf16) @ B^T, 16-wave split ----------
// Occupancy experiment done RIGHT (R13 spilled because 512-thread waves need
// 128 regs/lane): TPB=1024, 16 waves = 2 row-halves x 8 col-strips of the
// BM=32 x full-N tile. Per-lane state halves: acc[8]=32 regs + af 4 + bf 4 +
// temps ~15 = ~55 combined, inside the 64-reg budget that launch_bounds
// (1024,8) imposes for 2 blocks/CU -> 32 waves/CU (R6: 16). K-loop, B path,
// XOR-swizzled A tile, and the (R13-correctness-proven) 2-pass epilogue are
// verbatim from the champion kernels. Cost accepted: per-block B doubles ->
// 1 GB L2 B-traffic (~30 us at 34.5 TB/s, overlapped).
#define BM   32
#define TPB2 1024
#define CPAD 132                 // epilogue f32 LDS row stride (128+4)
#define EPW8 (8 * CPAD)          // floats per wave epilogue region (4224 B)

__global__ __launch_bounds__(TPB2, 8)
void gemm_sim_kernel(const float* __restrict__ A,
                     const unsigned short* __restrict__ Bsw,
                     float* __restrict__ C) {
  __shared__ float Tbuf[16 * EPW8];   // 67584 B (union: first 8 KB = A-tile)
  unsigned char* Als = reinterpret_cast<unsigned char*>(Tbuf);
  int t  = threadIdx.x;
  int m0 = blockIdx.x * BM;

  // ---- stage A: 32 rows x 128 f32 -> bf16, XOR-swizzled (rows 256 B) ----
  // 1024 threads x 4 f32 (8B LDS write; XOR bit4 preserves 8B alignment).
  {
    int row = t >> 5, c4 = t & 31;
    float4 v = *reinterpret_cast<const float4*>(A + (size_t)(m0 + row) * LOW_DIM + c4 * 4);
    uint2 q;
    q.x = f2bf(v.x) | ((unsigned)f2bf(v.y) << 16);
    q.y = f2bf(v.z) | ((unsigned)f2bf(v.w) << 16);
    *reinterpret_cast<uint2*>(Als + row * 256 + ((c4 * 8) ^ ((row & 7) << 4))) = q;
  }
  __syncthreads();

  int lane = t & 63;
  int w    = t >> 6;               // 0..15
  int h    = w >> 3;               // row-half: rows [h*16, h*16+16)
  int s    = w & 7;                // col-strip: cols [s*128, s*128+128)
  int lr   = lane & 15;
  int hi   = lane >> 4;            // 0..3
  int lkb  = hi * 16;

  f32x4 acc[8];
  #pragma unroll
  for (int n = 0; n < 8; ++n)
    acc[n] = (f32x4){0.f, 0.f, 0.f, 0.f};

  #pragma unroll
  for (int kk = 0; kk < 4; ++kk) {             // K = 4 x 32
    int kb  = kk * 64 + lkb;
    int row = h * 16 + lr;
    bf16x8 af = *reinterpret_cast<const bf16x8*>(Als + row * 256 + (kb ^ ((row & 7) << 4)));
    #pragma unroll
    for (int n = 0; n < 8; ++n) {
      int g = s * 8 + n;                       // 16-class group
      bf16x8 bf = *reinterpret_cast<const bf16x8*>(
          Bsw + ((size_t)(g * 4 + kk) * 64 + lane) * 8);   // coalesced 1KB/wave
      acc[n] = __builtin_amdgcn_mfma_f32_16x16x32_bf16(af, bf, acc[n], 0, 0, 0);
    }
  }
  __syncthreads();   // A-tile dead for ALL waves before epilogue reuses the union

  // ---- per-wave-private epilogue: two 8-row transpose passes (wave-local,
  //      in-order DS; correctness-proven in R13). D layout: row = hi*4+r,
  //      col = lane&15. Pass p covers D rows 8p..8p+7 (hi>>1 == p writes;
  //      buffer row = (hi&1)*4 + r). Readback: 512B chunks per row. ----
  float* myT = Tbuf + w * EPW8;
  #pragma unroll
  for (int p = 0; p < 2; ++p) {
    if ((hi >> 1) == p) {
      int rbase = (hi & 1) * 4;
      #pragma unroll
      for (int n = 0; n < 8; ++n) {
        #pragma unroll
        for (int r = 0; r < 4; ++r)
          myT[(rbase + r) * CPAD + n * 16 + lr] = acc[n][r];
      }
    }
    #pragma unroll
    for (int it = 0; it < 4; ++it) {
      int idx = it * 64 + lane;
      int row = idx >> 5, c4 = idx & 31;       // row 0..7, f32x4 chunk 0..31
      f32x4 v = *reinterpret_cast<const f32x4*>(myT + row * CPAD + c4 * 4);
      int col = s * 128 + c4 * 4;
      if (col < NUM_CLASS) {   // only strip 7 tail masked; 1000 % 4 == 0
        *reinterpret_cast<f32x4*>(
            C + (size_t)(m0 + h * 16 + p * 8 + row) * NUM_CLASS + col) = v;
      }
    }
  }
}

extern "C" void kernel_launch(void* const* d_in, const int* in_sizes, int n_in,
                              void* d_out, int out_size, void* d_ws, size_t ws_size,
                              hipStream_t stream) {
  const float* pred_feat = (const float*)d_in[0];   // [1024,128]
  const int*   labels    = (const int*)d_in[1];     // [1024]
  const float* protos    = (const float*)d_in[2];   // [1000,128]
  const float* feat      = (const float*)d_in[3];   // [65536,128]
  float* out = (float*)d_out;                       // [65536,1000]

  unsigned short* protos_sw = (unsigned short*)d_ws;  // 256 KB fragment-swizzled

  proto_update_kernel<<<NPAD, 128, 0, stream>>>(pred_feat, labels, protos, protos_sw);
  gemm_sim_kernel<<<B_SIM / BM, TPB2, 0, stream>>>(feat, protos_sw, out);
}